// Round 3
// baseline (295.912 us; speedup 1.0000x reference)
//
#include <hip/hip_runtime.h>
#include <math.h>

// Problem constants (from setup_inputs): N=262144, D=128, C=1024.
// Embeddings: float32 (reference dtype). Output: float32 scalar (confirmed
// by R1 evidence: bf16 write read back as ~0 through an fp32 view).
// Labels: nominally int32 per harness contract; int64 fallback auto-detected.
#define NUM_CLASSES 1024

// label accessor: mode32=1 -> plain int32 array; mode32=0 -> int64 array,
// read the low word of entry i. Mask to [0,1024) for memory safety.
__device__ __forceinline__ int get_label(const int* __restrict__ l, int i, int mode32) {
    return l[mode32 ? i : (i << 1)] & (NUM_CLASSES - 1);
}

// ---------------- Kernel 0: detect labels dtype ----------------
// int64 labels (values < 2^31) have all-zero high words at odd int32 indices.
// int32 labels have random values in [0,1024) there -> ~surely nonzero.
__global__ void detect_kernel(const int* __restrict__ labels32,
                              int* __restrict__ flag) {   // flag=1 -> int32 mode
    int i = threadIdx.x;                 // 128 threads
    if (labels32[2 * i + 1] != 0) atomicOr(flag, 1);
}

// ---------------- Kernel 1: per-class histogram of labels ----------------
__global__ void hist_kernel(const int* __restrict__ labels, int n,
                            int* __restrict__ counts,
                            const int* __restrict__ flag) {
    __shared__ int h[NUM_CLASSES];
    const int mode32 = *flag;
    for (int i = threadIdx.x; i < NUM_CLASSES; i += blockDim.x) h[i] = 0;
    __syncthreads();
    for (int i = blockIdx.x * blockDim.x + threadIdx.x; i < n;
         i += gridDim.x * blockDim.x) {
        atomicAdd(&h[get_label(labels, i, mode32)], 1);
    }
    __syncthreads();
    for (int i = threadIdx.x; i < NUM_CLASSES; i += blockDim.x) {
        int v = h[i];
        if (v) atomicAdd(&counts[i], v);
    }
}

// ---------------- Kernel 2: exclusive scan of counts (1 block) ----------------
__global__ void scan_kernel(const int* __restrict__ counts,
                            int* __restrict__ offsets,
                            int* __restrict__ cursor) {
    __shared__ int tmp[NUM_CLASSES];
    int tid = threadIdx.x;           // blockDim.x == 1024
    int v = counts[tid];
    tmp[tid] = v;
    __syncthreads();
    for (int off = 1; off < NUM_CLASSES; off <<= 1) {
        int add = (tid >= off) ? tmp[tid - off] : 0;
        __syncthreads();
        tmp[tid] += add;
        __syncthreads();
    }
    int excl = tmp[tid] - v;
    offsets[tid] = excl;
    cursor[tid]  = excl;
}

// ---------------- Kernel 3: scatter sample indices into class order ----------------
__global__ void scatter_kernel(const int* __restrict__ labels, int n,
                               int* __restrict__ cursor,
                               int* __restrict__ sorted,
                               const int* __restrict__ flag) {
    const int mode32 = *flag;
    int i = blockIdx.x * blockDim.x + threadIdx.x;
    if (i < n) {
        int pos = atomicAdd(&cursor[get_label(labels, i, mode32)], 1);
        sorted[pos] = i;
    }
}

// ---------------- Kernel 4: per-class normalized sum + loss contribution ----------------
// One block of 512 threads (8 waves) per class. Wave w handles rows
// start+w, start+w+8, ... Lane l holds fp32 row elements 2l, 2l+1 (float2).
// Identity: sum_{i in c} dot(emb_i, proto_c) = ||sum_{i in c} norm(emb_i)||
// (prototype has the same direction as the class sum), so
// per_class = (count - ||sum of normalized rows||) / count.
#define WPB 8
__global__ __launch_bounds__(512) void class_sum_kernel(
        const float* __restrict__ emb,      // N x 128 fp32
        const int* __restrict__ sorted,
        const int* __restrict__ offsets,
        const int* __restrict__ counts,
        float* __restrict__ accum) {        // accum[0]=loss_sum, accum[1]=n_valid
    const int c     = blockIdx.x;
    const int start = offsets[c];
    const int count = counts[c];
    const int wave  = threadIdx.x >> 6;
    const int lane  = threadIdx.x & 63;

    float a0 = 0.0f, a1 = 0.0f;
    for (int r = wave; r < count; r += WPB) {
        const int idx = sorted[start + r];
        const float2 v = *(const float2*)(emb + (size_t)idx * 128 + 2 * lane);
        float sq = v.x * v.x + v.y * v.y;
        #pragma unroll
        for (int off = 32; off; off >>= 1) sq += __shfl_xor(sq, off, 64);
        float inv = 1.0f / fmaxf(sqrtf(sq), 1e-12f);
        a0 += v.x * inv;
        a1 += v.y * inv;
    }

    // Reduce partial sums across the 8 waves: s2[w][lane] = (a0, a1)
    __shared__ float2 s2[WPB][64];
    s2[wave][lane] = make_float2(a0, a1);
    __syncthreads();

    __shared__ float red[128];
    if (threadIdx.x < 128) {
        // element d = 2*l + hi of the 128-dim class sum
        int l = threadIdx.x >> 1;      // lane that held it
        int hi = threadIdx.x & 1;      // 0 -> a0 (elem 2l), 1 -> a1 (elem 2l+1)
        float t = 0.0f;
        #pragma unroll
        for (int w = 0; w < WPB; w++) {
            float2 v = s2[w][l];
            t += hi ? v.y : v.x;
        }
        red[threadIdx.x] = t * t;
    }
    __syncthreads();
    if (threadIdx.x < 64) {
        float x = red[threadIdx.x] + red[threadIdx.x + 64];
        #pragma unroll
        for (int off = 32; off; off >>= 1) x += __shfl_xor(x, off, 64);
        if (threadIdx.x == 0 && count >= 2) {
            float nrm = sqrtf(x);                       // = sum over class of sim
            float per_class = ((float)count - nrm) / (float)count;
            atomicAdd(&accum[0], per_class);
            atomicAdd(&accum[1], 1.0f);
        }
    }
}

// ---------------- Kernel 5: finalize scalar (fp32 output) ----------------
__global__ void finalize_kernel(const float* __restrict__ accum,
                                float* __restrict__ out) {
    if (threadIdx.x == 0 && blockIdx.x == 0) {
        float nv = accum[1];
        out[0] = (nv > 0.0f) ? (accum[0] / nv) : 0.0f;
    }
}

extern "C" void kernel_launch(void* const* d_in, const int* in_sizes, int n_in,
                              void* d_out, int out_size, void* d_ws, size_t ws_size,
                              hipStream_t stream) {
    const float* emb  = (const float*)d_in[0];   // fp32, N x 128
    const int* labels = (const int*)d_in[1];     // int32 (or int64 low-word mode)
    // d_in[2] = num_classes (device scalar) — grid sizes must be host-side;
    // problem fixes C=1024 (setup_inputs), hard-coded as NUM_CLASSES.

    const int n = in_sizes[1];                // 262144 samples

    // Workspace layout
    char* ws = (char*)d_ws;
    int*   counts  = (int*)(ws + 0);                      // 1024 ints
    int*   offsets = (int*)(ws + 4096);                   // 1024 ints
    int*   cursor  = (int*)(ws + 8192);                   // 1024 ints
    float* accum   = (float*)(ws + 12288);                // 4 floats
    int*   flag    = (int*)(ws + 12304);                  // labels-dtype flag
    int*   sorted  = (int*)(ws + 16384);                  // n ints

    // Zero counts + accum + flag (ws is poisoned with 0xAA before every call)
    hipMemsetAsync(ws, 0, 4096, stream);                  // counts
    hipMemsetAsync(ws + 12288, 0, 32, stream);            // accum + flag

    detect_kernel<<<1, 128, 0, stream>>>(labels, flag);
    hist_kernel<<<256, 256, 0, stream>>>(labels, n, counts, flag);
    scan_kernel<<<1, NUM_CLASSES, 0, stream>>>(counts, offsets, cursor);
    scatter_kernel<<<(n + 255) / 256, 256, 0, stream>>>(labels, n, cursor, sorted, flag);
    class_sum_kernel<<<NUM_CLASSES, 512, 0, stream>>>(emb, sorted, offsets, counts, accum);
    finalize_kernel<<<1, 64, 0, stream>>>(accum, (float*)d_out);
}

// Round 4
// 261.699 us; speedup vs baseline: 1.1307x; 1.1307x over previous
//
#include <hip/hip_runtime.h>
#include <math.h>

// Problem constants (from setup_inputs): N=262144, D=128, C=1024.
// Embeddings: float32. Output: float32 scalar. Labels: int32 per harness
// contract, with int64 fallback auto-detected (flag kernel).
#define NUM_CLASSES 1024
#define HIST_CHUNK 2048      // samples per hist/scatter block

__device__ __forceinline__ int get_label(const int* __restrict__ l, int i, int mode32) {
    return l[mode32 ? i : (i << 1)] & (NUM_CLASSES - 1);
}

// ---------------- Kernel 0: detect labels dtype ----------------
__global__ void detect_kernel(const int* __restrict__ labels32,
                              int* __restrict__ flag) {   // flag=1 -> int32 mode
    int i = threadIdx.x;                 // 128 threads
    if (labels32[2 * i + 1] != 0) atomicOr(flag, 1);
}

// ---------------- Kernel 1: per-block partial histograms (NO global atomics) ----------------
__global__ void hist_kernel(const int* __restrict__ labels, int n,
                            int* __restrict__ partials,     // [numBlocks][1024]
                            const int* __restrict__ flag) {
    __shared__ int h[NUM_CLASSES];
    const int mode32 = *flag;
    for (int i = threadIdx.x; i < NUM_CLASSES; i += blockDim.x) h[i] = 0;
    __syncthreads();
    const int base = blockIdx.x * HIST_CHUNK;
    for (int k = threadIdx.x; k < HIST_CHUNK; k += blockDim.x) {
        int i = base + k;
        if (i < n) atomicAdd(&h[get_label(labels, i, mode32)], 1);
    }
    __syncthreads();
    for (int c = threadIdx.x; c < NUM_CLASSES; c += blockDim.x)
        partials[blockIdx.x * NUM_CLASSES + c] = h[c];
}

// ---------------- Kernel 2: scan (1 block, 1024 thr) ----------------
// counts[c] = sum_b partials[b][c]; offsets = exclusive scan of counts;
// partials[b][c] is rewritten IN PLACE to the global base offset for
// (block b, class c) — consumed by scatter_kernel's LDS cursors.
__global__ void scan_kernel(int* __restrict__ partials, int numBlocks,
                            int* __restrict__ offsets,
                            int* __restrict__ counts) {
    __shared__ int tmp[NUM_CLASSES];
    const int c = threadIdx.x;            // blockDim.x == 1024
    int sum = 0;
    for (int b = 0; b < numBlocks; b++) sum += partials[b * NUM_CLASSES + c];
    tmp[c] = sum;
    __syncthreads();
    for (int off = 1; off < NUM_CLASSES; off <<= 1) {
        int add = (c >= off) ? tmp[c - off] : 0;
        __syncthreads();
        tmp[c] += add;
        __syncthreads();
    }
    const int excl = tmp[c] - sum;
    offsets[c] = excl;
    counts[c]  = sum;
    int running = excl;
    for (int b = 0; b < numBlocks; b++) {
        int p = partials[b * NUM_CLASSES + c];
        partials[b * NUM_CLASSES + c] = running;
        running += p;
    }
}

// ---------------- Kernel 3: scatter via LDS cursors (NO global atomics) ----------------
__global__ void scatter_kernel(const int* __restrict__ labels, int n,
                               const int* __restrict__ partials, // per-block bases
                               int* __restrict__ sorted,
                               const int* __restrict__ flag) {
    __shared__ int cur[NUM_CLASSES];
    const int mode32 = *flag;
    for (int c = threadIdx.x; c < NUM_CLASSES; c += blockDim.x)
        cur[c] = partials[blockIdx.x * NUM_CLASSES + c];
    __syncthreads();
    const int base = blockIdx.x * HIST_CHUNK;
    for (int k = threadIdx.x; k < HIST_CHUNK; k += blockDim.x) {
        int i = base + k;
        if (i < n) {
            int pos = atomicAdd(&cur[get_label(labels, i, mode32)], 1);  // LDS atomic
            sorted[pos] = i;
        }
    }
}

// ---------------- Kernel 4: per-class normalized sum + loss ----------------
// One block (8 waves) per class. 16 lanes per row -> each wave handles 4 rows
// per iteration; lane sub holds row dims [4*sub..4*sub+3] and [64+4*sub..+3]
// as two float4s. Shuffle reduce is 4 steps (within the 16-lane group).
// Identity: sum_{i in c} dot(emb_i, proto_c) = ||sum_{i in c} norm(emb_i)||,
// so per_class = (count - ||sum||) / count.
#define WPB 8
__global__ __launch_bounds__(512) void class_sum_kernel(
        const float* __restrict__ emb,      // N x 128 fp32
        const int* __restrict__ sorted,
        const int* __restrict__ offsets,
        const int* __restrict__ counts,
        float* __restrict__ accum) {        // accum[0]=loss_sum, accum[1]=n_valid
    const int c     = blockIdx.x;
    const int start = offsets[c];
    const int count = counts[c];
    const int wave  = threadIdx.x >> 6;
    const int lane  = threadIdx.x & 63;
    const int g     = lane >> 4;            // row-group 0..3 within wave
    const int sub   = lane & 15;            // lane within row

    float4 aLo = make_float4(0.f, 0.f, 0.f, 0.f);
    float4 aHi = make_float4(0.f, 0.f, 0.f, 0.f);

    for (int r = wave * 4 + g; r < count; r += WPB * 4) {
        const int idx = sorted[start + r];
        const float4* row = (const float4*)(emb + (size_t)idx * 128);
        float4 v0 = row[sub];
        float4 v1 = row[sub + 16];
        float sq = v0.x*v0.x + v0.y*v0.y + v0.z*v0.z + v0.w*v0.w
                 + v1.x*v1.x + v1.y*v1.y + v1.z*v1.z + v1.w*v1.w;
        sq += __shfl_xor(sq, 1, 64);
        sq += __shfl_xor(sq, 2, 64);
        sq += __shfl_xor(sq, 4, 64);
        sq += __shfl_xor(sq, 8, 64);
        float inv = 1.0f / fmaxf(sqrtf(sq), 1e-12f);
        aLo.x += v0.x * inv; aLo.y += v0.y * inv; aLo.z += v0.z * inv; aLo.w += v0.w * inv;
        aHi.x += v1.x * inv; aHi.y += v1.y * inv; aHi.z += v1.z * inv; aHi.w += v1.w * inv;
    }

    // Reduce 32 partial vectors (8 waves x 4 groups) of 128 dims.
    __shared__ float s[WPB * 4][16][8];     // 16 KB
    {
        float* dst = s[wave * 4 + g][sub];
        dst[0] = aLo.x; dst[1] = aLo.y; dst[2] = aLo.z; dst[3] = aLo.w;
        dst[4] = aHi.x; dst[5] = aHi.y; dst[6] = aHi.z; dst[7] = aHi.w;
    }
    __syncthreads();

    __shared__ float red[128];
    if (threadIdx.x < 128) {
        const int d  = threadIdx.x;
        const int dd = d & 63;
        const int sb = dd >> 2;
        const int j  = (d >> 6) * 4 + (dd & 3);
        float t = 0.0f;
        #pragma unroll
        for (int k = 0; k < WPB * 4; k++) t += s[k][sb][j];
        red[d] = t * t;
    }
    __syncthreads();
    if (threadIdx.x < 64) {
        float x = red[threadIdx.x] + red[threadIdx.x + 64];
        #pragma unroll
        for (int off = 32; off; off >>= 1) x += __shfl_xor(x, off, 64);
        if (threadIdx.x == 0 && count >= 2) {
            float nrm = sqrtf(x);                       // = sum over class of sim
            float per_class = ((float)count - nrm) / (float)count;
            atomicAdd(&accum[0], per_class);
            atomicAdd(&accum[1], 1.0f);
        }
    }
}

// ---------------- Kernel 5: finalize scalar (fp32 output) ----------------
__global__ void finalize_kernel(const float* __restrict__ accum,
                                float* __restrict__ out) {
    if (threadIdx.x == 0 && blockIdx.x == 0) {
        float nv = accum[1];
        out[0] = (nv > 0.0f) ? (accum[0] / nv) : 0.0f;
    }
}

extern "C" void kernel_launch(void* const* d_in, const int* in_sizes, int n_in,
                              void* d_out, int out_size, void* d_ws, size_t ws_size,
                              hipStream_t stream) {
    const float* emb  = (const float*)d_in[0];   // fp32, N x 128
    const int* labels = (const int*)d_in[1];     // int32 (int64 handled via flag)
    const int n = in_sizes[1];                   // 262144 samples
    const int numBlocks = (n + HIST_CHUNK - 1) / HIST_CHUNK;   // 128

    // Workspace layout (~1.55 MB)
    char* ws = (char*)d_ws;
    int*   counts   = (int*)(ws + 0);                       // 1024 ints
    int*   offsets  = (int*)(ws + 4096);                    // 1024 ints
    float* accum    = (float*)(ws + 8192);                  // 4 floats
    int*   flag     = (int*)(ws + 8208);                    // labels-dtype flag
    int*   sorted   = (int*)(ws + 16384);                   // n ints (1 MB)
    int*   partials = (int*)(ws + 16384 + (size_t)n * 4);   // numBlocks*1024 ints

    hipMemsetAsync(ws + 8192, 0, 32, stream);               // accum + flag

    detect_kernel<<<1, 128, 0, stream>>>(labels, flag);
    hist_kernel<<<numBlocks, 256, 0, stream>>>(labels, n, partials, flag);
    scan_kernel<<<1, NUM_CLASSES, 0, stream>>>(partials, numBlocks, offsets, counts);
    scatter_kernel<<<numBlocks, 256, 0, stream>>>(labels, n, partials, sorted, flag);
    class_sum_kernel<<<NUM_CLASSES, 512, 0, stream>>>(emb, sorted, offsets, counts, accum);
    finalize_kernel<<<1, 64, 0, stream>>>(accum, (float*)d_out);
}

// Round 5
// 255.540 us; speedup vs baseline: 1.1580x; 1.0241x over previous
//
#include <hip/hip_runtime.h>
#include <math.h>

// Problem constants (from setup_inputs): N=262144, D=128, C=1024.
// Embeddings: float32. Output: float32 scalar. Labels: int32 per harness
// contract, int64 tolerated via uniform per-block detection (high words of
// int64 labels are 0 at odd int32 indices; int32 labels in [0,1024) make
// P(8 sampled odd words all zero) = 1024^-8 ~ 0).
#define NUM_CLASSES 1024
#define HIST_CHUNK 2048            // samples per hist/scatter block
#define NB 128                     // number of hist/scatter blocks (N/HIST_CHUNK)

__device__ __forceinline__ int detect_mode32(const int* __restrict__ l) {
    // uniform scalar loads; 1 -> labels are int32, 0 -> int64 (read low words)
    return (l[1] | l[3] | l[5] | l[7] | l[9] | l[11] | l[13] | l[15]) != 0;
}

__device__ __forceinline__ int get_label(const int* __restrict__ l, int i, int mode32) {
    return l[mode32 ? i : (i << 1)] & (NUM_CLASSES - 1);
}

// ---------------- Kernel 1: per-block partial histograms (transposed out) ----------------
__global__ void hist_kernel(const int* __restrict__ labels, int n,
                            int* __restrict__ pT) {        // [C][NB]
    __shared__ int h[NUM_CLASSES];
    const int mode32 = detect_mode32(labels);
    for (int i = threadIdx.x; i < NUM_CLASSES; i += blockDim.x) h[i] = 0;
    __syncthreads();
    const int base = blockIdx.x * HIST_CHUNK;
    for (int k = threadIdx.x; k < HIST_CHUNK; k += blockDim.x) {
        int i = base + k;
        if (i < n) atomicAdd(&h[get_label(labels, i, mode32)], 1);
    }
    __syncthreads();
    for (int c = threadIdx.x; c < NUM_CLASSES; c += blockDim.x)
        pT[c * NB + blockIdx.x] = h[c];
}

// ---------------- Kernel 2a: per-class prefix along blocks (wave per class) ----------------
// pT[c][b] := sum_{b'<b} pT[c][b'] (exclusive); totals[c] = full sum.
__global__ __launch_bounds__(512) void scanA_kernel(int* __restrict__ pT,
                                                    int* __restrict__ totals) {
    const int wave = threadIdx.x >> 6;
    const int lane = threadIdx.x & 63;
    const int c = blockIdx.x * 8 + wave;        // 128 blocks x 8 waves = 1024
    int* p = pT + c * NB;
    const int v0 = p[2 * lane];
    const int v1 = p[2 * lane + 1];
    int s = v0 + v1;
    #pragma unroll
    for (int d = 1; d < 64; d <<= 1) {
        int t = __shfl_up(s, d, 64);
        if (lane >= d) s += t;
    }
    const int base = s - v0 - v1;               // exclusive prefix before this pair
    p[2 * lane]     = base;
    p[2 * lane + 1] = base + v0;
    if (lane == 63) totals[c] = s;
}

// ---------------- Kernel 2b: cross-class exclusive scan (1 block) ----------------
__global__ void scanB_kernel(const int* __restrict__ totals,
                             int* __restrict__ offsets,
                             int* __restrict__ counts,
                             float* __restrict__ accum,
                             int* __restrict__ ticket) {
    __shared__ int tmp[NUM_CLASSES];
    const int c = threadIdx.x;                  // blockDim.x == 1024
    const int v = totals[c];
    tmp[c] = v;
    __syncthreads();
    for (int off = 1; off < NUM_CLASSES; off <<= 1) {
        int add = (c >= off) ? tmp[c - off] : 0;
        __syncthreads();
        tmp[c] += add;
        __syncthreads();
    }
    offsets[c] = tmp[c] - v;
    counts[c]  = v;
    if (c == 0) { accum[0] = 0.0f; accum[1] = 0.0f; *ticket = 0; }
}

// ---------------- Kernel 3: scatter via LDS cursors (no global atomics) ----------------
__global__ void scatter_kernel(const int* __restrict__ labels, int n,
                               const int* __restrict__ pT,
                               const int* __restrict__ offsets,
                               int* __restrict__ sorted) {
    __shared__ int cur[NUM_CLASSES];
    const int mode32 = detect_mode32(labels);
    for (int c = threadIdx.x; c < NUM_CLASSES; c += blockDim.x)
        cur[c] = offsets[c] + pT[c * NB + blockIdx.x];
    __syncthreads();
    const int base = blockIdx.x * HIST_CHUNK;
    for (int k = threadIdx.x; k < HIST_CHUNK; k += blockDim.x) {
        int i = base + k;
        if (i < n) {
            int pos = atomicAdd(&cur[get_label(labels, i, mode32)], 1);  // LDS atomic
            sorted[pos] = i;
        }
    }
}

// ---------------- Kernel 4: per-class normalized sum + loss (+finalize) ----------------
// One block (8 waves) per class. 16 lanes per row; wave handles 4 rows/iter.
// Identity: sum_{i in c} dot(emb_i, proto_c) = ||sum_{i in c} norm(emb_i)||,
// so per_class = (count - ||sum||) / count. Last block (ticket) finalizes.
#define WPB 8
__global__ __launch_bounds__(512) void class_sum_kernel(
        const float* __restrict__ emb,      // N x 128 fp32
        const int* __restrict__ sorted,
        const int* __restrict__ offsets,
        const int* __restrict__ counts,
        float* __restrict__ accum,          // [0]=loss_sum, [1]=n_valid
        int* __restrict__ ticket,
        float* __restrict__ out) {
    const int c     = blockIdx.x;
    const int start = offsets[c];
    const int count = counts[c];
    const int wave  = threadIdx.x >> 6;
    const int lane  = threadIdx.x & 63;
    const int g     = lane >> 4;            // row-group 0..3 within wave
    const int sub   = lane & 15;            // lane within row

    float4 aLo = make_float4(0.f, 0.f, 0.f, 0.f);
    float4 aHi = make_float4(0.f, 0.f, 0.f, 0.f);

    for (int r = wave * 4 + g; r < count; r += WPB * 4) {
        const int idx = sorted[start + r];
        const float4* row = (const float4*)(emb + (size_t)idx * 128);
        float4 v0 = row[sub];
        float4 v1 = row[sub + 16];
        float sq = v0.x*v0.x + v0.y*v0.y + v0.z*v0.z + v0.w*v0.w
                 + v1.x*v1.x + v1.y*v1.y + v1.z*v1.z + v1.w*v1.w;
        sq += __shfl_xor(sq, 1, 64);
        sq += __shfl_xor(sq, 2, 64);
        sq += __shfl_xor(sq, 4, 64);
        sq += __shfl_xor(sq, 8, 64);
        float inv = 1.0f / fmaxf(sqrtf(sq), 1e-12f);
        aLo.x += v0.x * inv; aLo.y += v0.y * inv; aLo.z += v0.z * inv; aLo.w += v0.w * inv;
        aHi.x += v1.x * inv; aHi.y += v1.y * inv; aHi.z += v1.z * inv; aHi.w += v1.w * inv;
    }

    // Reduce 32 partial vectors (8 waves x 4 groups) of 128 dims.
    __shared__ float s[WPB * 4][16][8];     // 16 KB
    {
        float* dst = s[wave * 4 + g][sub];
        dst[0] = aLo.x; dst[1] = aLo.y; dst[2] = aLo.z; dst[3] = aLo.w;
        dst[4] = aHi.x; dst[5] = aHi.y; dst[6] = aHi.z; dst[7] = aHi.w;
    }
    __syncthreads();

    __shared__ float red[128];
    if (threadIdx.x < 128) {
        const int d  = threadIdx.x;
        const int dd = d & 63;
        const int sb = dd >> 2;
        const int j  = (d >> 6) * 4 + (dd & 3);
        float t = 0.0f;
        #pragma unroll
        for (int k = 0; k < WPB * 4; k++) t += s[k][sb][j];
        red[d] = t * t;
    }
    __syncthreads();
    if (threadIdx.x < 64) {
        float x = red[threadIdx.x] + red[threadIdx.x + 64];
        #pragma unroll
        for (int off = 32; off; off >>= 1) x += __shfl_xor(x, off, 64);
        if (threadIdx.x == 0) {
            if (count >= 2) {
                float nrm = sqrtf(x);                   // = sum over class of sim
                float per_class = ((float)count - nrm) / (float)count;
                atomicAdd(&accum[0], per_class);
                atomicAdd(&accum[1], 1.0f);
            }
            __threadfence();
            int old = atomicAdd(ticket, 1);
            if (old == NUM_CLASSES - 1) {
                // device-scope atomic reads (cross-XCD safe)
                float ls = atomicAdd(&accum[0], 0.0f);
                float nv = atomicAdd(&accum[1], 0.0f);
                out[0] = (nv > 0.0f) ? (ls / nv) : 0.0f;
            }
        }
    }
}

extern "C" void kernel_launch(void* const* d_in, const int* in_sizes, int n_in,
                              void* d_out, int out_size, void* d_ws, size_t ws_size,
                              hipStream_t stream) {
    const float* emb  = (const float*)d_in[0];   // fp32, N x 128
    const int* labels = (const int*)d_in[1];     // int32 (int64 handled inline)
    const int n = in_sizes[1];                   // 262144 samples

    // Workspace layout (~1.55 MB)
    char* ws = (char*)d_ws;
    int*   counts  = (int*)(ws + 0);                       // 1024 ints
    int*   offsets = (int*)(ws + 4096);                    // 1024 ints
    int*   totals  = (int*)(ws + 8192);                    // 1024 ints
    float* accum   = (float*)(ws + 12288);                 // 2 floats
    int*   ticket  = (int*)(ws + 12304);                   // 1 int
    int*   sorted  = (int*)(ws + 16384);                   // n ints (1 MB)
    int*   pT      = (int*)(ws + 16384 + (size_t)n * 4);   // C*NB ints (512 KB)

    hist_kernel <<<NB, 256, 0, stream>>>(labels, n, pT);
    scanA_kernel<<<NB, 512, 0, stream>>>(pT, totals);
    scanB_kernel<<<1, NUM_CLASSES, 0, stream>>>(totals, offsets, counts, accum, ticket);
    scatter_kernel<<<NB, 256, 0, stream>>>(labels, n, pT, offsets, sorted);
    class_sum_kernel<<<NUM_CLASSES, 512, 0, stream>>>(emb, sorted, offsets, counts,
                                                      accum, ticket, (float*)d_out);
}